// Round 1
// baseline (629.309 us; speedup 1.0000x reference)
//
#include <hip/hip_runtime.h>
#include <hip/hip_bf16.h>

#define SEQ   16384
#define DIM   2048
#define CHUNK 256
#define NCHUNK (SEQ / CHUNK)   // 64

typedef __attribute__((ext_vector_type(8))) short  short8;
typedef __attribute__((ext_vector_type(4))) short  short4v;
typedef __attribute__((ext_vector_type(4))) float  floatx4;

static __device__ __forceinline__ float bf2f(short s) {
    return __uint_as_float(((unsigned)(unsigned short)s) << 16);
}
static __device__ __forceinline__ short f2bf(float f) {
    unsigned u = __float_as_uint(f);
    u += 0x7fff + ((u >> 16) & 1);   // RNE
    return (short)(u >> 16);
}

// ---------- fp32 -> bf16 cast, float4 vectorized ----------
__global__ void cast_kernel(const float* __restrict__ in, short* __restrict__ out, int n4) {
    int i = blockIdx.x * blockDim.x + threadIdx.x;
    if (i >= n4) return;
    float4 v = ((const float4*)in)[i];
    short4v s;
    s.x = f2bf(v.x); s.y = f2bf(v.y); s.z = f2bf(v.z); s.w = f2bf(v.w);
    ((short4v*)out)[i] = s;
}

// ---------- bf16 GEMM, C[m][n] = sum_k A[m][k]*B[n][k]  (both K-contiguous) ----------
// M=SEQ, N=DIM, K=DIM. 128x128 tile, BK=32, 256 threads = 4 waves, wave => 64x64 quadrant.
// FUSE==0: store bf16 C. FUSE==1: store fp32 C + xs*dskip.
template<int FUSE>
__global__ __launch_bounds__(256, 2)
void gemm_bt(const short* __restrict__ A, const short* __restrict__ B,
             short* __restrict__ Cbf, float* __restrict__ Cf,
             const float* __restrict__ xs, const float* __restrict__ dskip)
{
    constexpr int K = DIM;
    __shared__ alignas(16) short As[128 * 32];
    __shared__ alignas(16) short Bs[128 * 32];

    const int tid = threadIdx.x;
    const int m0  = blockIdx.y * 128;
    const int n0  = blockIdx.x * 128;

    // staging: 512 chunks of 16B per tile, 2 per thread per operand
    const int c0 = tid, c1 = tid + 256;
    const short* ga0 = A + (size_t)(m0 + (c0 >> 2)) * K + (c0 & 3) * 8;
    const short* ga1 = A + (size_t)(m0 + (c1 >> 2)) * K + (c1 & 3) * 8;
    const short* gb0 = B + (size_t)(n0 + (c0 >> 2)) * K + (c0 & 3) * 8;
    const short* gb1 = B + (size_t)(n0 + (c1 >> 2)) * K + (c1 & 3) * 8;
    short* la0 = &As[c0 * 8];
    short* la1 = &As[c1 * 8];
    short* lb0 = &Bs[c0 * 8];
    short* lb1 = &Bs[c1 * 8];

    const int lane = tid & 63;
    const int wv   = tid >> 6;
    const int wm   = (wv >> 1) * 64;
    const int wn   = (wv & 1) * 64;
    const int l16  = lane & 15;
    const int quad = lane >> 4;

    floatx4 acc[4][4] = {};

    for (int kk = 0; kk < K; kk += 32) {
        __builtin_amdgcn_global_load_lds(ga0 + kk, la0, 16, 0, 0);
        __builtin_amdgcn_global_load_lds(ga1 + kk, la1, 16, 0, 0);
        __builtin_amdgcn_global_load_lds(gb0 + kk, lb0, 16, 0, 0);
        __builtin_amdgcn_global_load_lds(gb1 + kk, lb1, 16, 0, 0);
        __syncthreads();

        short8 aV[4], bV[4];
        #pragma unroll
        for (int i = 0; i < 4; i++)
            aV[i] = *(const short8*)&As[(wm + i * 16 + l16) * 32 + quad * 8];
        #pragma unroll
        for (int i = 0; i < 4; i++)
            bV[i] = *(const short8*)&Bs[(wn + i * 16 + l16) * 32 + quad * 8];

        #pragma unroll
        for (int mi = 0; mi < 4; mi++)
            #pragma unroll
            for (int ni = 0; ni < 4; ni++)
                acc[mi][ni] = __builtin_amdgcn_mfma_f32_16x16x32_bf16(
                    aV[mi], bV[ni], acc[mi][ni], 0, 0, 0);
        __syncthreads();
    }

    // epilogue: C tile element (row = quad*4 + r, col = l16) per 16x16 frag
    if (FUSE == 0) {
        #pragma unroll
        for (int mi = 0; mi < 4; mi++) {
            int rb = m0 + wm + mi * 16 + quad * 4;
            #pragma unroll
            for (int ni = 0; ni < 4; ni++) {
                int cc = n0 + wn + ni * 16 + l16;
                #pragma unroll
                for (int r = 0; r < 4; r++)
                    Cbf[(size_t)(rb + r) * DIM + cc] = f2bf(acc[mi][ni][r]);
            }
        }
    } else {
        float dsk[4];
        #pragma unroll
        for (int ni = 0; ni < 4; ni++) dsk[ni] = dskip[n0 + wn + ni * 16 + l16];
        #pragma unroll
        for (int mi = 0; mi < 4; mi++) {
            int rb = m0 + wm + mi * 16 + quad * 4;
            #pragma unroll
            for (int ni = 0; ni < 4; ni++) {
                int cc = n0 + wn + ni * 16 + l16;
                #pragma unroll
                for (int r = 0; r < 4; r++) {
                    size_t idx = (size_t)(rb + r) * DIM + cc;
                    Cf[idx] = acc[mi][ni][r] + xs[idx] * dsk[ni];
                }
            }
        }
    }
}

// ---------- scan pass 1: per-chunk local final state (zero init) ----------
__global__ void scan_pass1(const short* __restrict__ bx, const float* __restrict__ lam,
                           float* __restrict__ blockLast)
{
    int n     = blockIdx.x * 256 + threadIdx.x;
    int chunk = blockIdx.y;
    float lm  = lam[n];
    const short* p = bx + (size_t)chunk * CHUNK * DIM + n;
    float h = 0.f;
    #pragma unroll 8
    for (int i = 0; i < CHUNK; i++)
        h = fmaf(lm, h, bf2f(p[(size_t)i * DIM]));
    blockLast[(size_t)chunk * DIM + n] = h;
}

// ---------- scan pass 2: exclusive prefix over chunks (in place) ----------
__global__ void scan_pass2(float* __restrict__ blockLast, const float* __restrict__ lam)
{
    int n    = blockIdx.x * 256 + threadIdx.x;
    float lm = lam[n];
    float p  = lm;
    #pragma unroll
    for (int i = 0; i < 8; i++) p = p * p;    // lam^256
    float carry = 0.f;
    for (int c = 0; c < NCHUNK; c++) {
        float t = blockLast[(size_t)c * DIM + n];
        blockLast[(size_t)c * DIM + n] = carry;
        carry = fmaf(p, carry, t);
    }
}

// ---------- scan pass 3: apply carry, write hs (bf16, in place over bx) ----------
__global__ void scan_pass3(short* __restrict__ bxh, const float* __restrict__ lam,
                           const float* __restrict__ carry)
{
    int n     = blockIdx.x * 256 + threadIdx.x;
    int chunk = blockIdx.y;
    float lm  = lam[n];
    float h   = carry[(size_t)chunk * DIM + n];
    short* p  = bxh + (size_t)chunk * CHUNK * DIM + n;
    #pragma unroll 8
    for (int i = 0; i < CHUNK; i++) {
        h = fmaf(lm, h, bf2f(p[(size_t)i * DIM]));
        p[(size_t)i * DIM] = f2bf(h);
    }
}

extern "C" void kernel_launch(void* const* d_in, const int* in_sizes, int n_in,
                              void* d_out, int out_size, void* d_ws, size_t ws_size,
                              hipStream_t stream)
{
    const float* xs    = (const float*)d_in[0];
    const float* lam   = (const float*)d_in[1];
    const float* w_in  = (const float*)d_in[2];
    const float* c_out = (const float*)d_in[3];
    const float* dskip = (const float*)d_in[4];
    float* out = (float*)d_out;

    // ws layout (total ~80.5 MiB):
    //   [0,   64M) : bx / hs  bf16  [SEQ][DIM]
    //   [64M, 72M) : w_in     bf16  [DIM][DIM]
    //   [72M, 80M) : c_out    bf16  [DIM][DIM]
    //   [80M, +512K): chunk carries fp32 [NCHUNK][DIM]
    char*  ws    = (char*)d_ws;
    short* bxh   = (short*)ws;
    short* w_bf  = (short*)(ws + (size_t)64 * 1024 * 1024);
    short* c_bf  = (short*)(ws + (size_t)72 * 1024 * 1024);
    float* blkl  = (float*)(ws + (size_t)80 * 1024 * 1024);
    // xs_bf16 lives in the front 64 MiB of d_out (dead before final GEMM writes it)
    short* xs_bf = (short*)d_out;

    cast_kernel<<<SEQ * DIM / 4 / 256, 256, 0, stream>>>(xs, xs_bf, SEQ * DIM / 4);
    cast_kernel<<<DIM * DIM / 4 / 256, 256, 0, stream>>>(w_in, w_bf, DIM * DIM / 4);
    cast_kernel<<<DIM * DIM / 4 / 256, 256, 0, stream>>>(c_out, c_bf, DIM * DIM / 4);

    dim3 ggrid(DIM / 128, SEQ / 128);   // (16, 128)
    gemm_bt<0><<<ggrid, 256, 0, stream>>>(xs_bf, w_bf, bxh, nullptr, nullptr, nullptr);

    dim3 sgrid(DIM / 256, NCHUNK);      // (8, 64)
    scan_pass1<<<sgrid, 256, 0, stream>>>(bxh, lam, blkl);
    scan_pass2<<<DIM / 256, 256, 0, stream>>>(blkl, lam);
    scan_pass3<<<sgrid, 256, 0, stream>>>(bxh, lam, blkl);

    gemm_bt<1><<<ggrid, 256, 0, stream>>>(bxh, c_bf, nullptr, out, xs, dskip);
}